// Round 18
// baseline (267.180 us; speedup 1.0000x reference)
//
#include <hip/hip_runtime.h>

// Resample2d: backward warp of input1 (B,C,H,W) by flow input2 (B,2,H,W).
// Bilinear, border padding (clamp). B=8 C=64 H=256 W=448, all fp32.
//
// Round 18: R15/R17 pipeline (78.4us, proven twice), taller tile.
// 64x32 px tile, TPB=512: same y-margins amortized over 2x rows ->
// staging amplification 40*96/(64*32)=1.875x (was 3x, -260MB L2 reads)
// and LDS 2x16KB -> 4 blocks x 8 waves = 32/32 wave slots (100% cap,
// was 75%). Staging source pattern is IDENTICAL to R15 (WC=96, same
// per-wave 384/384/256B segments) - the R13/R16 regressions came from
// changed source mappings, which this avoids.
//  - 960 real f4 / 512 thr: 2 uniform chunks/thread with the global src
//    CLAMPED per-lane for f4>=960 (dup 16B reads = L2 hits); LDS dest
//    stays lane-linear (f4*16B); pad region 960..1023 never read.
//  - Counted vmcnt: prologue (2); loop (E) = [2 gl(c+2), 1 store] -> (3).
//  - Margins +-4 rows / 16+15 cols; outliers (P~6e-5) exact fallback.
//  - Quad-pixel threads: 1 f32x4 nt-store/channel, wave row = 256B span.

typedef float f32x4 __attribute__((ext_vector_type(4)));

#define RB 8
#define RC 64
#define RH 256
#define RW 448
#define RHW (RH * RW)
#define TPB 512
#define TLX 64
#define TLY 32
#define CS 4
#define CPB (RC / CS)               // 16
#define NXT (RW / TLX)              // 7
#define NYT (RH / TLY)              // 8
#define NBLK (RB * CS * NYT * NXT)  // 1792
#define NXCD 8
#define WR 40                       // window rows
#define WC 96                       // window cols (= LDS row stride, floats)
#define WF4R (WC / 4)               // 24 f4 per row
#define WF4 (WR * WF4R)             // 960 real f4
#define BUF_F4 1024                 // padded to 2 * 512 (uniform staging)
#define WFLOATS (BUF_F4 * 4)        // 4096 floats = 16384 B per buffer
#define NCHUNK 2                    // 1024 f4 / 512 threads
#define QPX 4                       // pixels per thread (one x-quad)

#define GLOAD_LDS16(gp, lp)                                                   \
    __builtin_amdgcn_global_load_lds(                                         \
        (const __attribute__((address_space(1))) void*)(gp),                  \
        (__attribute__((address_space(3))) void*)(lp), 16, 0, 0)

__global__ __launch_bounds__(TPB, 8) void resample2d_kernel(
    const float* __restrict__ img,   // (B,C,H,W)
    const float* __restrict__ flow,  // (B,2,H,W)
    float* __restrict__ out)         // (B,C,H,W)
{
    __shared__ float sm[2][WFLOATS];   // 32768 B

    // Bijective XCD-chunked swizzle (1792 % 8 == 0); id minor-orders xt,
    // then yt, cg, b: each XCD chunk = 224 consecutive tiles of one image.
    int bid = blockIdx.x;
    int id = (bid & (NXCD - 1)) * (NBLK / NXCD) + (bid >> 3);
    int xt = id % NXT;
    int t2 = id / NXT;
    int yt = t2 % NYT;
    int t3 = t2 / NYT;
    int cg = t3 % CS;
    int b  = t3 / CS;

    int tx = xt * TLX, ty = yt * TLY;
    int xs0 = min(max(tx - 16, 0), RW - WC);   // 16-float aligned
    int ys0 = min(max(ty - 4, 0),  RH - WR);

    int tid = threadIdx.x;
    int w = tid >> 6, l = tid & 63;
    int row = w * 4 + (l >> 4);                // tile row 0..31
    int x = tx + (l & 15) * 4;                 // quad base column
    int y = ty + row;
    int po = y * RW + x;                       // within-plane quad offset

    const float* flb = flow + (size_t)b * 2 * RHW;

    // ---- Coord precompute for the quad (channel-invariant) ----
    unsigned offA[QPX], offB[QPX];   // byte offsets into the 16KB window
    float wxa[QPX], wya[QPX];
    f32x4 fx4 = *(const f32x4*)(flb + po);
    f32x4 fy4 = *(const f32x4*)(flb + RHW + po);
    #pragma unroll
    for (int k = 0; k < QPX; ++k) {
        float fx = fx4[k];
        float fy = fy4[k];
        float xr = fminf(fmaxf((float)(x + k) + fx, 0.f), (float)(RW - 1));
        float yr = fminf(fmaxf((float)y + fy, 0.f), (float)(RH - 1));
        float x0f = floorf(xr), y0f = floorf(yr);
        float wx = xr - x0f, wy = yr - y0f;
        int x0 = (int)x0f, y0 = (int)y0f;
        int shift = (x0 == RW - 1) ? 1 : 0;    // border: pair base -1, wx:=1
        int lx = x0 - xs0 - shift;
        int ly0 = y0 - ys0;
        int yflag = (y0 < RH - 1) ? 1 : 0;
        if ((unsigned)lx <= WC - 2 && (unsigned)ly0 < WR &&
            (unsigned)(ly0 + yflag) < WR) {
            offA[k] = (unsigned)((ly0 * WC + lx) * 4);
            offB[k] = offA[k] + (unsigned)(yflag * (WC * 4));
        } else {
            offA[k] = 0xFFFFFFFFu;             // outlier sentinel
            offB[k] = 0;
        }
        wxa[k] = shift ? 1.0f : wx;
        wya[k] = wy;
    }

    const float* imgc = img + ((size_t)b * RC + (size_t)cg * CPB) * RHW;
    float* outc       = out + ((size_t)b * RC + (size_t)cg * CPB) * RHW;
    const float* gwin = imgc + (size_t)ys0 * RW + xs0;

    // Staging offsets (once). Global src clamped per-lane for f4 >= 960
    // (dup reads of the last block, L2 hits); LDS dest stays lane-linear
    // (f4*16B; pad region 960..1023 is written junk, never read).
    int srcOff[NCHUNK], ldsOff[NCHUNK];
    #pragma unroll
    for (int kk = 0; kk < NCHUNK; ++kk) {
        int f4 = kk * TPB + tid;
        int f4c = min(f4, WF4 - 1);
        int r = f4c / WF4R;
        int c4 = f4c - r * WF4R;
        srcOff[kk] = r * RW + c4 * 4;          // float offset in global
        ldsOff[kk] = f4 * 4;                   // float offset in LDS (linear)
    }

    // ---- Prologue: drain stray vm ops, stage ch0 -> buf0, ch1 -> buf1 ----
    asm volatile("s_waitcnt vmcnt(0)" ::: "memory");
    #pragma unroll
    for (int kk = 0; kk < NCHUNK; ++kk)
        GLOAD_LDS16(gwin + srcOff[kk], &sm[0][ldsOff[kk]]);
    #pragma unroll
    for (int kk = 0; kk < NCHUNK; ++kk)
        GLOAD_LDS16(gwin + RHW + srcOff[kk], &sm[1][ldsOff[kk]]);
    __builtin_amdgcn_sched_barrier(0);
    asm volatile("s_waitcnt vmcnt(2)" ::: "memory");   // buf0 ready
    __builtin_amdgcn_s_barrier();
    __builtin_amdgcn_sched_barrier(0);

    #pragma unroll 1
    for (int c = 0; c < CPB; ++c) {
        const float* sb = sm[c & 1];
        float* q = outc + (size_t)c * RHW;

        // (A) LDS gather + blend for the quad, then ONE vec4 nt-store.
        f32x4 vq;
        #pragma unroll
        for (int k = 0; k < QPX; ++k) {
            unsigned oa = offA[k];
            float v;
            if (__builtin_expect(oa != 0xFFFFFFFFu, 1)) {
                const char* bp = (const char*)sb;
                float a0 = *(const float*)(bp + oa);
                float a1 = *(const float*)(bp + oa + 4);
                float b0 = *(const float*)(bp + offB[k]);
                float b1 = *(const float*)(bp + offB[k] + 4);
                float vA = a0 + (a1 - a0) * wxa[k];
                float vB = b0 + (b1 - b0) * wxa[k];
                v = vA + (vB - vA) * wya[k];
            } else {
                // Exact fallback (P ~ 6e-5): recompute from flow, gather.
                float fx = flb[po + k];
                float fy = flb[RHW + po + k];
                float xr = fminf(fmaxf((float)(x + k) + fx, 0.f),
                                 (float)(RW - 1));
                float yr = fminf(fmaxf((float)y + fy, 0.f), (float)(RH - 1));
                float x0f = floorf(xr), y0f = floorf(yr);
                float ax = xr - x0f, ay = yr - y0f;
                int x0 = (int)x0f, y0 = (int)y0f;
                int x1 = min(x0 + 1, RW - 1), y1 = min(y0 + 1, RH - 1);
                const float* pp = imgc + (size_t)c * RHW;
                float v00 = pp[y0 * RW + x0], v01 = pp[y0 * RW + x1];
                float v10 = pp[y1 * RW + x0], v11 = pp[y1 * RW + x1];
                float vA = v00 + (v01 - v00) * ax;
                float vB = v10 + (v11 - v10) * ax;
                v = vA + (vB - vA) * ay;
            }
            vq[k] = v;
        }
        __builtin_nontemporal_store(vq, (f32x4*)(q + po));

        // (C) block done reading buf[c&1].
        asm volatile("s_waitcnt lgkmcnt(0)" ::: "memory");
        __builtin_amdgcn_s_barrier();
        __builtin_amdgcn_sched_barrier(0);

        // (D) stage ch c+2 into the freed buffer (clamped: uniform count).
        {
            int cn = min(c + 2, CPB - 1);
            const float* g = gwin + (size_t)cn * RHW;
            float* dst = sm[c & 1];
            #pragma unroll
            for (int kk = 0; kk < NCHUNK; ++kk)
                GLOAD_LDS16(g + srcOff[kk], &dst[ldsOff[kk]]);
        }
        __builtin_amdgcn_sched_barrier(0);   // pin (D) before the wait

        // (E) counted wait. Queue newest-first: [2 gl(c+2), 1 store(c),
        //     2 gl(c+1), ...]. vmcnt(3) drains through iter c+1's buffer.
        asm volatile("s_waitcnt vmcnt(3)" ::: "memory");
        __builtin_amdgcn_s_barrier();
        __builtin_amdgcn_sched_barrier(0);
    }
}

extern "C" void kernel_launch(void* const* d_in, const int* in_sizes, int n_in,
                              void* d_out, int out_size, void* d_ws, size_t ws_size,
                              hipStream_t stream) {
    const float* img  = (const float*)d_in[0];
    const float* flow = (const float*)d_in[1];
    float* out = (float*)d_out;

    resample2d_kernel<<<NBLK, TPB, 0, stream>>>(img, flow, out);
}

// Round 19
// 78.416 us; speedup vs baseline: 3.4072x; 3.4072x over previous
//
#include <hip/hip_runtime.h>

// Resample2d: backward warp of input1 (B,C,H,W) by flow input2 (B,2,H,W).
// Bilinear, border padding (clamp). B=8 C=64 H=256 W=448, all fp32.
//
// Round 19: exact revert to R15/R17 (78.4us, reproduced twice) - FINAL.
// Post-mortems R13/R16/R18 established that every staging-geometry change
// (stride, shift-swizzle, taller tile) breaks the L2/L3 residency that
// makes the 3x window amplification nearly free, costing 2-3x. The LDS
// bank conflicts (~1.5e7) are at the random-scatter floor. Remaining gap
// to the 56.5us HBM floor is structural (L2-tier staging + barriers).
//
// Design (proven):
//  - 64x16 px tiles x 16 channels; quad-pixel threads (4 consecutive x)
//    -> one f32x4 nt-store per channel (wave row = full 256B aligned span).
//  - Window 32x96 fp32 = 12KB/buf, dbuf 24KB -> 6 blocks/CU.
//  - Staging: 3 exec-uniform global_load_lds(16B)/thread (768 f4 = 3x256).
//  - Counted vmcnt pipeline: prologue vmcnt(3); per-channel (E) wait
//    vmcnt(4) = [3 gl(c+2), 1 store(c)] -> drains c+1's buffer exactly.
//  - lgkmcnt(0)+barrier before overwriting the just-read buffer.
//  - Outliers beyond the +-8-row/16-col margins take an exact global
//    fallback (over-draining vmcnt is safe).
//  - Bijective XCD-chunked blockIdx swizzle for L2 locality.

typedef float f32x4 __attribute__((ext_vector_type(4)));

#define RB 8
#define RC 64
#define RH 256
#define RW 448
#define RHW (RH * RW)
#define TPB 256
#define TLX 64
#define TLY 16
#define CS 4
#define CPB (RC / CS)               // 16
#define NXT (RW / TLX)              // 7
#define NYT (RH / TLY)              // 16
#define NBLK (RB * CS * NYT * NXT)  // 3584
#define NXCD 8
#define WR 32                       // window rows
#define WC 96                       // window cols (= LDS row stride, floats)
#define WF4R (WC / 4)               // 24 f4 per row
#define WF4 (WR * WF4R)             // 768 = 3 * 256 (exec-uniform staging)
#define WFLOATS (WR * WC)           // 3072 floats = 12288 B
#define NCHUNK (WF4 / TPB)          // 3
#define QPX 4                       // pixels per thread (one x-quad)

#define GLOAD_LDS16(gp, lp)                                                   \
    __builtin_amdgcn_global_load_lds(                                         \
        (const __attribute__((address_space(1))) void*)(gp),                  \
        (__attribute__((address_space(3))) void*)(lp), 16, 0, 0)

__global__ __launch_bounds__(TPB, 6) void resample2d_kernel(
    const float* __restrict__ img,   // (B,C,H,W)
    const float* __restrict__ flow,  // (B,2,H,W)
    float* __restrict__ out)         // (B,C,H,W)
{
    __shared__ float sm[2][WFLOATS];   // 24576 B

    // Bijective XCD-chunked swizzle (3584 % 8 == 0); id minor-orders xt,
    // then yt, cg, b: each XCD chunk = 448 consecutive tiles of one image.
    int bid = blockIdx.x;
    int id = (bid & (NXCD - 1)) * (NBLK / NXCD) + (bid >> 3);
    int xt = id % NXT;
    int t2 = id / NXT;
    int yt = t2 % NYT;
    int t3 = t2 / NYT;
    int cg = t3 % CS;
    int b  = t3 / CS;

    int tx = xt * TLX, ty = yt * TLY;
    int xs0 = min(max(tx - 16, 0), RW - WC);   // 16-float aligned
    int ys0 = min(max(ty - 8, 0),  RH - WR);

    int tid = threadIdx.x;
    int w = tid >> 6, l = tid & 63;
    int row = w * 4 + (l >> 4);                // tile row 0..15
    int x = tx + (l & 15) * 4;                 // quad base column
    int y = ty + row;
    int po = y * RW + x;                       // within-plane quad offset

    const float* flb = flow + (size_t)b * 2 * RHW;

    // ---- Coord precompute for the quad (channel-invariant) ----
    unsigned offA[QPX], offB[QPX];   // byte offsets into the 12KB window
    float wxa[QPX], wya[QPX];
    f32x4 fx4 = *(const f32x4*)(flb + po);
    f32x4 fy4 = *(const f32x4*)(flb + RHW + po);
    #pragma unroll
    for (int k = 0; k < QPX; ++k) {
        float fx = fx4[k];
        float fy = fy4[k];
        float xr = fminf(fmaxf((float)(x + k) + fx, 0.f), (float)(RW - 1));
        float yr = fminf(fmaxf((float)y + fy, 0.f), (float)(RH - 1));
        float x0f = floorf(xr), y0f = floorf(yr);
        float wx = xr - x0f, wy = yr - y0f;
        int x0 = (int)x0f, y0 = (int)y0f;
        int shift = (x0 == RW - 1) ? 1 : 0;    // border: pair base -1, wx:=1
        int lx = x0 - xs0 - shift;
        int ly0 = y0 - ys0;
        int yflag = (y0 < RH - 1) ? 1 : 0;
        if ((unsigned)lx <= WC - 2 && (unsigned)ly0 < WR &&
            (unsigned)(ly0 + yflag) < WR) {
            offA[k] = (unsigned)((ly0 * WC + lx) * 4);
            offB[k] = offA[k] + (unsigned)(yflag * (WC * 4));
        } else {
            offA[k] = 0xFFFFFFFFu;             // outlier sentinel
            offB[k] = 0;
        }
        wxa[k] = shift ? 1.0f : wx;
        wya[k] = wy;
    }

    const float* imgc = img + ((size_t)b * RC + (size_t)cg * CPB) * RHW;
    float* outc       = out + ((size_t)b * RC + (size_t)cg * CPB) * RHW;
    const float* gwin = imgc + (size_t)ys0 * RW + xs0;

    // Staging offsets (once): f4 = kk*256+tid -> (row=f4/24, c4=f4%24).
    int srcOff[NCHUNK], ldsOff[NCHUNK];
    #pragma unroll
    for (int kk = 0; kk < NCHUNK; ++kk) {
        int f4 = kk * TPB + tid;
        int r = f4 / WF4R;
        int c4 = f4 - r * WF4R;
        srcOff[kk] = r * RW + c4 * 4;          // float offset in global
        ldsOff[kk] = f4 * 4;                   // float offset in LDS (linear)
    }

    // ---- Prologue: drain stray vm ops, stage ch0 -> buf0, ch1 -> buf1 ----
    asm volatile("s_waitcnt vmcnt(0)" ::: "memory");
    #pragma unroll
    for (int kk = 0; kk < NCHUNK; ++kk)
        GLOAD_LDS16(gwin + srcOff[kk], &sm[0][ldsOff[kk]]);
    #pragma unroll
    for (int kk = 0; kk < NCHUNK; ++kk)
        GLOAD_LDS16(gwin + RHW + srcOff[kk], &sm[1][ldsOff[kk]]);
    __builtin_amdgcn_sched_barrier(0);
    asm volatile("s_waitcnt vmcnt(3)" ::: "memory");   // buf0 ready
    __builtin_amdgcn_s_barrier();
    __builtin_amdgcn_sched_barrier(0);

    #pragma unroll 1
    for (int c = 0; c < CPB; ++c) {
        const float* sb = sm[c & 1];
        float* q = outc + (size_t)c * RHW;

        // (A) LDS gather + blend for the quad, then ONE vec4 nt-store.
        f32x4 vq;
        #pragma unroll
        for (int k = 0; k < QPX; ++k) {
            unsigned oa = offA[k];
            float v;
            if (__builtin_expect(oa != 0xFFFFFFFFu, 1)) {
                const char* bp = (const char*)sb;
                float a0 = *(const float*)(bp + oa);
                float a1 = *(const float*)(bp + oa + 4);
                float b0 = *(const float*)(bp + offB[k]);
                float b1 = *(const float*)(bp + offB[k] + 4);
                float vA = a0 + (a1 - a0) * wxa[k];
                float vB = b0 + (b1 - b0) * wxa[k];
                v = vA + (vB - vA) * wya[k];
            } else {
                // Exact fallback (rare): recompute from flow, gather global.
                float fx = flb[po + k];
                float fy = flb[RHW + po + k];
                float xr = fminf(fmaxf((float)(x + k) + fx, 0.f),
                                 (float)(RW - 1));
                float yr = fminf(fmaxf((float)y + fy, 0.f), (float)(RH - 1));
                float x0f = floorf(xr), y0f = floorf(yr);
                float ax = xr - x0f, ay = yr - y0f;
                int x0 = (int)x0f, y0 = (int)y0f;
                int x1 = min(x0 + 1, RW - 1), y1 = min(y0 + 1, RH - 1);
                const float* pp = imgc + (size_t)c * RHW;
                float v00 = pp[y0 * RW + x0], v01 = pp[y0 * RW + x1];
                float v10 = pp[y1 * RW + x0], v11 = pp[y1 * RW + x1];
                float vA = v00 + (v01 - v00) * ax;
                float vB = v10 + (v11 - v10) * ax;
                v = vA + (vB - vA) * ay;
            }
            vq[k] = v;
        }
        __builtin_nontemporal_store(vq, (f32x4*)(q + po));

        // (C) block done reading buf[c&1].
        asm volatile("s_waitcnt lgkmcnt(0)" ::: "memory");
        __builtin_amdgcn_s_barrier();
        __builtin_amdgcn_sched_barrier(0);

        // (D) stage ch c+2 into the freed buffer (clamped: uniform count).
        {
            int cn = min(c + 2, CPB - 1);
            const float* g = gwin + (size_t)cn * RHW;
            float* dst = sm[c & 1];
            #pragma unroll
            for (int kk = 0; kk < NCHUNK; ++kk)
                GLOAD_LDS16(g + srcOff[kk], &dst[ldsOff[kk]]);
        }
        __builtin_amdgcn_sched_barrier(0);   // pin (D) before the wait

        // (E) counted wait. Queue newest-first: [3 gl(c+2), 1 store(c),
        //     3 gl(c+1), ...]. vmcnt(4) drains through iter c+1's buffer.
        asm volatile("s_waitcnt vmcnt(4)" ::: "memory");
        __builtin_amdgcn_s_barrier();
        __builtin_amdgcn_sched_barrier(0);
    }
}

extern "C" void kernel_launch(void* const* d_in, const int* in_sizes, int n_in,
                              void* d_out, int out_size, void* d_ws, size_t ws_size,
                              hipStream_t stream) {
    const float* img  = (const float*)d_in[0];
    const float* flow = (const float*)d_in[1];
    float* out = (float*)d_out;

    resample2d_kernel<<<NBLK, TPB, 0, stream>>>(img, flow, out);
}